// Round 19
// baseline (197.712 us; speedup 1.0000x reference)
//
#include <hip/hip_runtime.h>
#include <hip/hip_bf16.h>

typedef signed char i8;
typedef unsigned char u8;
typedef unsigned short u16;
typedef unsigned int u32;
typedef __attribute__((ext_vector_type(4))) int i32x4;

#define GLD16(g, l) __builtin_amdgcn_global_load_lds((const __attribute__((address_space(1))) u32*)(g), (__attribute__((address_space(3))) u32*)(l), 16, 0, 0)

// symmetric i8 quantization scales
#define SB (4.5f / 127.f)
#define SQ (2.0f / 127.f)
#define INV_SB (127.f / 4.5f)
#define INV_SQ (127.f / 2.0f)
#define TWO_S (2.0f * SB * SQ)

__device__ __forceinline__ u32 flipf(float f) {
    u32 u = __float_as_uint(f);
    return (u >> 31) ? ~u : (u | 0x80000000u);
}

__device__ __forceinline__ float unflipf(u32 k) {
    return __uint_as_float((k >> 31) ? (k ^ 0x80000000u) : ~k);
}

__device__ __forceinline__ int q8(float x, float invs) {
    return __float2int_rn(fminf(fmaxf(x * invs, -127.f), 127.f));
}

// bilinear 14->28 taps (jax.image.resize, half-pixel, edge-renormalized)
__device__ __forceinline__ void taps(int o, int& i0, int& i1, float& w0, float& w1) {
    int k = (o - 1) >> 1;
    float fy = (0.5f * (float)o - 0.25f) - (float)k;
    i0 = k; i1 = k + 1;
    w0 = 1.0f - fy; w1 = fy;
    if (i0 < 0)  { i0 = 0;  w0 = 0.0f; w1 = 1.0f; }
    if (i1 > 13) { i1 = 13; w1 = 0.0f; w0 = 1.0f; }
}

// k1: U = 3x3 box-sum of paired feat3 channels (+ minkey/qn2 init in low blocks)
__global__ __launch_bounds__(256) void u_init_kernel(
    const float* __restrict__ f3, float* __restrict__ U,
    u32* __restrict__ minkey, float* __restrict__ qn2) {
    int bid = blockIdx.x, tid = threadIdx.x;
    if (bid < 25) {
        int i = bid * 256 + tid;
        if (i < 6400) minkey[i] = 0xFFFFFFFFu;
        if (i < 6272) qn2[i] = 0.f;
    }
    int idx = bid * 256 + tid;
    if (idx >= 8 * 512 * 196) return;
    int b = idx / (512 * 196);
    int rem = idx % (512 * 196);
    int t = rem / 196;
    int yx = rem % 196;
    int y = yx / 14, x = yx % 14;
    const float* p0 = f3 + ((size_t)(b * 1024 + 2 * t)) * 196;
    const float* p1 = p0 + 196;
    float s = 0.f;
    #pragma unroll
    for (int dy = -1; dy <= 1; ++dy) {
        int yy = y + dy; if ((unsigned)yy >= 14u) continue;
        #pragma unroll
        for (int dx = -1; dx <= 1; ++dx) {
            int xx = x + dx; if ((unsigned)xx >= 14u) continue;
            s += p0[yy * 14 + xx] + p1[yy * 14 + xx];
        }
    }
    U[idx] = s;
}

// k2 (merged): [blocks 0..16383] memory-bank fp32->i8 (linear) + fp32 norms
//              [blocks 16384..19967] tiled q-embed (R12/R13 proven)
__global__ __launch_bounds__(256) void mbq_kernel(
    const float* __restrict__ mb, u8* __restrict__ mbb, float* __restrict__ mb2,
    const float* __restrict__ feat2, const float* __restrict__ U,
    u8* __restrict__ qb, float* __restrict__ qn2) {
    __shared__ float lds[3 * 64 * 29];
    const int bid0 = blockIdx.x;
    const int tid = threadIdx.x;

    if (bid0 < 16384) {
        float4 v = ((const float4*)(mb + (size_t)bid0 * 1024))[tid];
        u32 p = ((u32)(u8)(i8)q8(v.x, INV_SB))
              | ((u32)(u8)(i8)q8(v.y, INV_SB) << 8)
              | ((u32)(u8)(i8)q8(v.z, INV_SB) << 16)
              | ((u32)(u8)(i8)q8(v.w, INV_SB) << 24);
        ((u32*)(mbb + (size_t)bid0 * 1024))[tid] = p;
        float ssq = v.x * v.x + v.y * v.y + v.z * v.z + v.w * v.w;
        for (int s = 32; s; s >>= 1) ssq += __shfl_down(ssq, s);
        if ((tid & 63) == 0) lds[tid >> 6] = ssq;
        __syncthreads();
        if (tid == 0) mb2[bid0] = lds[0] + lds[1] + lds[2] + lds[3];
        return;
    }

    const int bid = bid0 - 16384;
    const int b = bid / (28 * 16);
    const int rem = bid % (28 * 16);
    const int h = rem / 16;
    const int chunk = rem % 16;
    const int lane = tid & 63;
    const int wg = tid >> 6;

    if (chunk < 8) {
        const int c0 = chunk * 64;
        for (int i = tid; i < 3 * 64 * 28; i += 256) {
            int r = i / 1792;
            int rr = i % 1792;
            int c = rr / 28, x = rr % 28;
            int y = h - 1 + r;
            lds[(r * 64 + c) * 29 + x] = ((unsigned)y < 28u)
                ? feat2[((size_t)(b * 512 + c0 + c) * 28 + y) * 28 + x] : 0.f;
        }
        __syncthreads();
        const float* rowp = &lds[lane * 29];
        #pragma unroll
        for (int wi = 0; wi < 7; ++wi) {
            const int w = wg * 7 + wi;
            float s = 0.f;
            #pragma unroll
            for (int r = 0; r < 3; ++r) {
                #pragma unroll
                for (int dx = -1; dx <= 1; ++dx) {
                    int x = w + dx;
                    if ((unsigned)x >= 28u) continue;
                    float wt = (r == 1 && dx == 0) ? 2.f : 1.f;
                    s += wt * rowp[r * 64 * 29 + x];
                }
            }
            float val = s * 0.1f;
            const int n = b * 784 + h * 28 + w;
            qb[(size_t)n * 1024 + c0 + lane] = (u8)(i8)q8(val, INV_SQ);
            float ss = val * val;
            for (int sft = 32; sft; sft >>= 1) ss += __shfl_down(ss, sft);
            if (lane == 0) atomicAdd(&qn2[n], ss);
        }
    } else {
        const int t0 = (chunk - 8) * 64;
        int y0, y1; float wy0, wy1;
        taps(h, y0, y1, wy0, wy1);
        for (int i = tid; i < 2 * 64 * 14; i += 256) {
            int r = i / 896;
            int rr = i % 896;
            int t = rr / 14, x = rr % 14;
            lds[(r * 64 + t) * 15 + x] =
                U[(size_t)(b * 512 + t0 + t) * 196 + (r ? y1 : y0) * 14 + x];
        }
        __syncthreads();
        const float* rp0 = &lds[lane * 15];
        const float* rp1 = &lds[(64 + lane) * 15];
        #pragma unroll
        for (int wi = 0; wi < 7; ++wi) {
            const int w = wg * 7 + wi;
            int x0, x1; float wx0, wx1;
            taps(w, x0, x1, wx0, wx1);
            float val = (wy0 * (wx0 * rp0[x0] + wx1 * rp0[x1])
                       + wy1 * (wx0 * rp1[x0] + wx1 * rp1[x1])) * (1.f / 18.f);
            const int n = b * 784 + h * 28 + w;
            qb[(size_t)n * 1024 + 512 + t0 + lane] = (u8)(i8)q8(val, INV_SQ);
            float ss = val * val;
            for (int sft = 32; sft; sft >>= 1) ss += __shfl_down(ss, sft);
            if (lane == 0) atomicAdd(&qn2[n], ss);
        }
    }
}

// 128x128-tile BK=64 i8 MFMA GEMM, 4-WAVE BLOCKS x 4 BLOCKS/CU: R13's
// verified internals (GLD16+XOR swizzle, burst frag reads, lgkmcnt(2)/(0)
// gates, 1 barrier + 1 vmcnt/tile) but the barrier domain shrinks 8->4
// waves and 4 independent domains/CU drift antiphase -> LDS-serve and MFMA
// from different blocks overlap instead of convoying. Fused min epilogue.
// M=6400 (6272 real), N=16384, K=1024 -> 16 K-tiles. Grid 50x128=6400.
__global__ __launch_bounds__(256, 4) void gemm_min_kernel(
    const u8* __restrict__ qb, const u8* __restrict__ mbb,
    const float* __restrict__ qn2, const float* __restrict__ mb2,
    u32* __restrict__ minkeys) {
    __shared__ __align__(16) u8 As[2][8192];    // [buf][128 rows x 64 B]
    __shared__ __align__(16) u8 Bs[2][8192];    // [buf][128 rows x 64 B]
    __shared__ u32 rowmin[128];

    const int tid = threadIdx.x;
    const int wid = tid >> 6;    // 0..3
    const int lane = tid & 63;
    const int wm = wid >> 1;     // 2 M-waves (64 rows each)
    const int wn = wid & 1;      // 2 N-waves (64 cols each)

    // XCD-aware bijective swizzle: 6400 blocks, 8 XCDs, 800/XCD.
    // 50 consecutive blocks per XCD share one 128KB B-panel.
    const int flat = blockIdx.x;
    const int swz = (flat & 7) * 800 + (flat >> 3);
    const int q0 = (swz % 50) * 128;   // q-row (M) panel
    const int m0 = (swz / 50) * 128;   // memory-bank (N) panel

    // staging: rows of 64 B (4 x 16B slots), 4 lanes/row; one GLD16 set
    // (256 lanes) covers 64 rows; j=0/1 -> rows 0-63 / 64-127.
    // LDS dest linear; global source slot XOR-swizzled with (row>>1)&3.
    const int rloc = wid * 16 + (lane >> 2);            // 0..63, + j*64
    const int sslot = (lane & 3) ^ ((lane >> 3) & 3);
    size_t gA[2], gB[2];
    u32 ldst[2];
    #pragma unroll
    for (int j = 0; j < 2; ++j) {
        gA[j] = (size_t)(q0 + rloc + j * 64) * 1024 + sslot * 16;
        gB[j] = (size_t)(m0 + rloc + j * 64) * 1024 + sslot * 16;
        ldst[j] = j * 4096 + wid * 1024;       // byte idx, wave-uniform
    }

    #define STAGE(T) { const int _t = (T); \
        GLD16(qb + gA[0] + _t * 64, &As[_t & 1][ldst[0]]); \
        GLD16(qb + gA[1] + _t * 64, &As[_t & 1][ldst[1]]); \
        GLD16(mbb + gB[0] + _t * 64, &Bs[_t & 1][ldst[0]]); \
        GLD16(mbb + gB[1] + _t * 64, &Bs[_t & 1][ldst[1]]); }

    // fragment reads: row = base + (lane&15), slot = (lane>>4) ^ ((row>>1)&3)
    const u32 arow = (u32)(wm * 64 + (lane & 15)) * 64;   // + m*1024 (bytes)
    const u32 brow = (u32)(wn * 64 + (lane & 15)) * 64;   // + n*1024
    const u32 sl = (u32)(((lane >> 4) ^ (((lane & 15) >> 1) & 3)) * 16);

    i32x4 acc[4][4] = {};
    i32x4 a[4], b[4];

    STAGE(0);
    asm volatile("s_waitcnt vmcnt(0)" ::: "memory");
    __builtin_amdgcn_s_barrier();
    __builtin_amdgcn_sched_barrier(0);

    for (int t = 0; t < 16; ++t) {
        const u8* Ab = &As[t & 1][0];
        const u8* Bb = &Bs[t & 1][0];

        // ---- burst: all 8 frag reads (order a0-3, b0-3)
        #pragma unroll
        for (int m = 0; m < 4; ++m) a[m] = *(const i32x4*)&Ab[arow + m * 1024 + sl];
        #pragma unroll
        for (int n = 0; n < 4; ++n) b[n] = *(const i32x4*)&Bb[brow + n * 1024 + sl];

        // ---- stage tile t+1 (other buffer; t-1 reads retired at t-1 end barrier)
        if (t < 15) STAGE(t + 1)

        // ---- H1: a x b01
        asm volatile("s_waitcnt lgkmcnt(2)" ::: "memory");
        __builtin_amdgcn_sched_barrier(0);
        __builtin_amdgcn_s_setprio(1);
        #pragma unroll
        for (int m = 0; m < 4; ++m)
            #pragma unroll
            for (int n = 0; n < 2; ++n)
                acc[m][n] = __builtin_amdgcn_mfma_i32_16x16x64_i8(a[m], b[n], acc[m][n], 0, 0, 0);
        __builtin_amdgcn_s_setprio(0);
        // ---- H2: a x b23
        asm volatile("s_waitcnt lgkmcnt(0)" ::: "memory");
        __builtin_amdgcn_sched_barrier(0);
        __builtin_amdgcn_s_setprio(1);
        #pragma unroll
        for (int m = 0; m < 4; ++m)
            #pragma unroll
            for (int n = 2; n < 4; ++n)
                acc[m][n] = __builtin_amdgcn_mfma_i32_16x16x64_i8(a[m], b[n], acc[m][n], 0, 0, 0);
        __builtin_amdgcn_s_setprio(0);

        // ---- tile end: next tile landed, publish buffers
        if (t < 15) { asm volatile("s_waitcnt vmcnt(0)" ::: "memory"); }
        __builtin_amdgcn_s_barrier();
        __builtin_amdgcn_sched_barrier(0);
    }

    // ---- epilogue: fused min over memory dim (d2 = qq + mb2 - 2*S*dot_i32)
    if (tid < 128) rowmin[tid] = 0xFFFFFFFFu;
    __syncthreads();

    float mb2v[4];
    #pragma unroll
    for (int n = 0; n < 4; ++n) mb2v[n] = mb2[m0 + wn * 64 + n * 16 + (lane & 15)];

    #pragma unroll
    for (int m = 0; m < 4; ++m) {
        #pragma unroll
        for (int r = 0; r < 4; ++r) {
            const int qrow = wm * 64 + m * 16 + (lane >> 4) * 4 + r;
            const float qq = qn2[q0 + qrow];
            float v = 3.4e38f;
            #pragma unroll
            for (int n = 0; n < 4; ++n) {
                float d2 = qq + mb2v[n] - TWO_S * (float)acc[m][n][r];
                v = fminf(v, d2);
            }
            #pragma unroll
            for (int s = 1; s < 16; s <<= 1) v = fminf(v, __shfl_xor(v, s));
            if ((lane & 15) == 0) atomicMin(&rowmin[qrow], flipf(v));
        }
    }
    __syncthreads();
    if (tid < 128) atomicMin(minkeys + q0 + tid, rowmin[tid]);
}

// per-image max + write patch scores
__global__ __launch_bounds__(256) void final_kernel(const u32* __restrict__ keys, float* __restrict__ out) {
    int b = blockIdx.x, tid = threadIdx.x;
    float mx = -3.4e38f;
    for (int i = tid; i < 784; i += 256) {
        float f = unflipf(keys[b * 784 + i]);
        out[8 + b * 784 + i] = f;
        mx = fmaxf(mx, f);
    }
    for (int s = 32; s; s >>= 1) mx = fmaxf(mx, __shfl_down(mx, s));
    __shared__ float sm[4];
    if ((tid & 63) == 0) sm[tid >> 6] = mx;
    __syncthreads();
    if (tid == 0) out[b] = fmaxf(fmaxf(sm[0], sm[1]), fmaxf(sm[2], sm[3]));
}

extern "C" void kernel_launch(void* const* d_in, const int* in_sizes, int n_in,
                              void* d_out, int out_size, void* d_ws, size_t ws_size,
                              hipStream_t stream) {
    const float* feat2 = (const float*)d_in[0];   // [8,512,28,28]
    const float* feat3 = (const float*)d_in[1];   // [8,1024,14,14]
    const float* mb    = (const float*)d_in[2];   // [16384,1024]
    float* out = (float*)d_out;                   // [8] image + [8,28,28] patch

    char* ws = (char*)d_ws;
    float* U      = (float*)(ws);                  // 3,211,264 B
    u8*    qb     = (u8*)   (ws + 3211264);        // 6400*1024 = 6,553,600 B (pad rows unused)
    u8*    mbb    = (u8*)   (ws + 9764864);        // 16,777,216 B
    float* qn2    = (float*)(ws + 26542080);       // 25,088 B
    float* mb2    = (float*)(ws + 26567168);       // 65,536 B
    u32*   minkey = (u32*)  (ws + 26632704);       // 25,600 B

    u_init_kernel<<<3136, 256, 0, stream>>>(feat3, U, minkey, qn2);
    mbq_kernel<<<19968, 256, 0, stream>>>(mb, mbb, mb2, feat2, U, qb, qn2);
    gemm_min_kernel<<<6400, 256, 0, stream>>>(qb, mbb, qn2, mb2, minkey);
    final_kernel<<<8, 256, 0, stream>>>(minkey, out);
}

// Round 20
// 183.837 us; speedup vs baseline: 1.0755x; 1.0755x over previous
//
#include <hip/hip_runtime.h>
#include <hip/hip_bf16.h>

typedef signed char i8;
typedef unsigned char u8;
typedef unsigned short u16;
typedef unsigned int u32;
typedef __attribute__((ext_vector_type(4))) int i32x4;

#define GLD16(g, l) __builtin_amdgcn_global_load_lds((const __attribute__((address_space(1))) u32*)(g), (__attribute__((address_space(3))) u32*)(l), 16, 0, 0)

// symmetric i8 quantization scales
#define SB (4.5f / 127.f)
#define SQ (2.0f / 127.f)
#define INV_SB (127.f / 4.5f)
#define INV_SQ (127.f / 2.0f)
#define TWO_S (2.0f * SB * SQ)

__device__ __forceinline__ u32 flipf(float f) {
    u32 u = __float_as_uint(f);
    return (u >> 31) ? ~u : (u | 0x80000000u);
}

__device__ __forceinline__ float unflipf(u32 k) {
    return __uint_as_float((k >> 31) ? (k ^ 0x80000000u) : ~k);
}

__device__ __forceinline__ int q8(float x, float invs) {
    return __float2int_rn(fminf(fmaxf(x * invs, -127.f), 127.f));
}

// bilinear 14->28 taps (jax.image.resize, half-pixel, edge-renormalized)
__device__ __forceinline__ void taps(int o, int& i0, int& i1, float& w0, float& w1) {
    int k = (o - 1) >> 1;
    float fy = (0.5f * (float)o - 0.25f) - (float)k;
    i0 = k; i1 = k + 1;
    w0 = 1.0f - fy; w1 = fy;
    if (i0 < 0)  { i0 = 0;  w0 = 0.0f; w1 = 1.0f; }
    if (i1 > 13) { i1 = 13; w1 = 0.0f; w0 = 1.0f; }
}

// k1: U = 3x3 box-sum of paired feat3 channels (+ minkey/qn2 init in low blocks)
__global__ __launch_bounds__(256) void u_init_kernel(
    const float* __restrict__ f3, float* __restrict__ U,
    u32* __restrict__ minkey, float* __restrict__ qn2) {
    int bid = blockIdx.x, tid = threadIdx.x;
    if (bid < 25) {
        int i = bid * 256 + tid;
        if (i < 6400) minkey[i] = 0xFFFFFFFFu;
        if (i < 6272) qn2[i] = 0.f;
    }
    int idx = bid * 256 + tid;
    if (idx >= 8 * 512 * 196) return;
    int b = idx / (512 * 196);
    int rem = idx % (512 * 196);
    int t = rem / 196;
    int yx = rem % 196;
    int y = yx / 14, x = yx % 14;
    const float* p0 = f3 + ((size_t)(b * 1024 + 2 * t)) * 196;
    const float* p1 = p0 + 196;
    float s = 0.f;
    #pragma unroll
    for (int dy = -1; dy <= 1; ++dy) {
        int yy = y + dy; if ((unsigned)yy >= 14u) continue;
        #pragma unroll
        for (int dx = -1; dx <= 1; ++dx) {
            int xx = x + dx; if ((unsigned)xx >= 14u) continue;
            s += p0[yy * 14 + xx] + p1[yy * 14 + xx];
        }
    }
    U[idx] = s;
}

// k2 (merged, q-FIRST so the LDS/VALU-bound q half overlaps the HBM-bound
// mb half instead of serializing behind it):
//   [blocks 0..3583]      tiled q-embed (R12/R13 proven)
//   [blocks 3584..19967]  memory-bank fp32->i8 (linear) + fp32 norms
__global__ __launch_bounds__(256) void mbq_kernel(
    const float* __restrict__ mb, u8* __restrict__ mbb, float* __restrict__ mb2,
    const float* __restrict__ feat2, const float* __restrict__ U,
    u8* __restrict__ qb, float* __restrict__ qn2) {
    __shared__ float lds[3 * 64 * 29];
    const int bid0 = blockIdx.x;
    const int tid = threadIdx.x;

    if (bid0 >= 3584) {
        // ---- memory bank: fp32 -> i8 (linear rows) + row norms
        const int mrow = bid0 - 3584;
        float4 v = ((const float4*)(mb + (size_t)mrow * 1024))[tid];
        u32 p = ((u32)(u8)(i8)q8(v.x, INV_SB))
              | ((u32)(u8)(i8)q8(v.y, INV_SB) << 8)
              | ((u32)(u8)(i8)q8(v.z, INV_SB) << 16)
              | ((u32)(u8)(i8)q8(v.w, INV_SB) << 24);
        ((u32*)(mbb + (size_t)mrow * 1024))[tid] = p;
        float ssq = v.x * v.x + v.y * v.y + v.z * v.z + v.w * v.w;
        for (int s = 32; s; s >>= 1) ssq += __shfl_down(ssq, s);
        if ((tid & 63) == 0) lds[tid >> 6] = ssq;
        __syncthreads();
        if (tid == 0) mb2[mrow] = lds[0] + lds[1] + lds[2] + lds[3];
        return;
    }

    // ---- tiled q-embed: block = (b, h, chunk-of-64-dims)
    const int bid = bid0;
    const int b = bid / (28 * 16);
    const int rem = bid % (28 * 16);
    const int h = rem / 16;
    const int chunk = rem % 16;
    const int lane = tid & 63;
    const int wg = tid >> 6;

    if (chunk < 8) {
        const int c0 = chunk * 64;
        for (int i = tid; i < 3 * 64 * 28; i += 256) {
            int r = i / 1792;
            int rr = i % 1792;
            int c = rr / 28, x = rr % 28;
            int y = h - 1 + r;
            lds[(r * 64 + c) * 29 + x] = ((unsigned)y < 28u)
                ? feat2[((size_t)(b * 512 + c0 + c) * 28 + y) * 28 + x] : 0.f;
        }
        __syncthreads();
        const float* rowp = &lds[lane * 29];
        #pragma unroll
        for (int wi = 0; wi < 7; ++wi) {
            const int w = wg * 7 + wi;
            float s = 0.f;
            #pragma unroll
            for (int r = 0; r < 3; ++r) {
                #pragma unroll
                for (int dx = -1; dx <= 1; ++dx) {
                    int x = w + dx;
                    if ((unsigned)x >= 28u) continue;
                    float wt = (r == 1 && dx == 0) ? 2.f : 1.f;
                    s += wt * rowp[r * 64 * 29 + x];
                }
            }
            float val = s * 0.1f;
            const int n = b * 784 + h * 28 + w;
            qb[(size_t)n * 1024 + c0 + lane] = (u8)(i8)q8(val, INV_SQ);
            float ss = val * val;
            for (int sft = 32; sft; sft >>= 1) ss += __shfl_down(ss, sft);
            if (lane == 0) atomicAdd(&qn2[n], ss);
        }
    } else {
        const int t0 = (chunk - 8) * 64;
        int y0, y1; float wy0, wy1;
        taps(h, y0, y1, wy0, wy1);
        for (int i = tid; i < 2 * 64 * 14; i += 256) {
            int r = i / 896;
            int rr = i % 896;
            int t = rr / 14, x = rr % 14;
            lds[(r * 64 + t) * 15 + x] =
                U[(size_t)(b * 512 + t0 + t) * 196 + (r ? y1 : y0) * 14 + x];
        }
        __syncthreads();
        const float* rp0 = &lds[lane * 15];
        const float* rp1 = &lds[(64 + lane) * 15];
        #pragma unroll
        for (int wi = 0; wi < 7; ++wi) {
            const int w = wg * 7 + wi;
            int x0, x1; float wx0, wx1;
            taps(w, x0, x1, wx0, wx1);
            float val = (wy0 * (wx0 * rp0[x0] + wx1 * rp0[x1])
                       + wy1 * (wx0 * rp1[x0] + wx1 * rp1[x1])) * (1.f / 18.f);
            const int n = b * 784 + h * 28 + w;
            qb[(size_t)n * 1024 + 512 + t0 + lane] = (u8)(i8)q8(val, INV_SQ);
            float ss = val * val;
            for (int sft = 32; sft; sft >>= 1) ss += __shfl_down(ss, sft);
            if (lane == 0) atomicAdd(&qn2[n], ss);
        }
    }
}

// R13 GEMM (verified best, 145us): 128x256-tile BK=64 i8 MFMA, both operands
// GLD16->LDS (XOR source swizzle), burst frag reads with lgkmcnt(2)/(0)
// gates, stage t+1, 1 barrier + 1 vmcnt per tile, 2 blocks/CU. Fused min.
// M=6400 (6272 real), N=16384, K=1024 -> 16 K-tiles.
__global__ __launch_bounds__(512, 4) void gemm_min_kernel(
    const u8* __restrict__ qb, const u8* __restrict__ mbb,
    const float* __restrict__ qn2, const float* __restrict__ mb2,
    u32* __restrict__ minkeys) {
    __shared__ __align__(16) u8 As[2][8192];    // [buf][128 rows x 64 B]
    __shared__ __align__(16) u8 Bs[2][16384];   // [buf][256 rows x 64 B]
    __shared__ u32 rowmin[128];

    const int tid = threadIdx.x;
    const int wid = tid >> 6;
    const int lane = tid & 63;
    const int wm = wid >> 2;   // 2 M-waves (64 rows each)
    const int wn = wid & 3;    // 4 N-waves (64 cols each)

    // XCD-aware bijective swizzle: 3200 blocks, 8 XCDs, 400/XCD.
    const int flat = blockIdx.x;
    const int swz = (flat & 7) * 400 + (flat >> 3);
    const int q0 = (swz % 50) * 128;   // q-row (M) panel
    const int m0 = (swz / 50) * 256;   // memory-bank (N) panel

    // staging: rows of 64 B (4 x 16B slots), 4 lanes/row; LDS dest linear,
    // global source slot XOR-swizzled with (row>>1)&3.
    const int rloc = wid * 16 + (lane >> 2);            // 0..127
    const int sslot = (lane & 3) ^ ((lane >> 3) & 3);
    const size_t gA  = (size_t)(q0 + rloc) * 1024 + sslot * 16;
    const size_t gB0 = (size_t)(m0 + rloc) * 1024 + sslot * 16;
    const size_t gB1 = (size_t)(m0 + 128 + rloc) * 1024 + sslot * 16;
    const u32 ldA = wid * 1024;                // byte idx, wave-uniform
    const u32 ldB1 = 8192 + wid * 1024;

    #define STAGE(T) { const int _t = (T); \
        GLD16(qb + gA + _t * 64, &As[_t & 1][ldA]); \
        GLD16(mbb + gB0 + _t * 64, &Bs[_t & 1][ldA]); \
        GLD16(mbb + gB1 + _t * 64, &Bs[_t & 1][ldB1]); }

    // fragment reads: row = base + (lane&15), slot = (lane>>4) ^ ((row>>1)&3)
    const u32 arow = (u32)(wm * 64 + (lane & 15)) * 64;   // + m*1024 (bytes)
    const u32 brow = (u32)(wn * 64 + (lane & 15)) * 64;   // + n*1024
    const u32 sl = (u32)(((lane >> 4) ^ (((lane & 15) >> 1) & 3)) * 16);

    i32x4 acc[4][4] = {};
    i32x4 a[4], b[4];

    STAGE(0);
    asm volatile("s_waitcnt vmcnt(0)" ::: "memory");
    __builtin_amdgcn_s_barrier();
    __builtin_amdgcn_sched_barrier(0);

    for (int t = 0; t < 16; ++t) {
        const u8* Ab = &As[t & 1][0];
        const u8* Bb = &Bs[t & 1][0];

        // ---- burst: all 8 frag reads (order a0-3, b0-3)
        #pragma unroll
        for (int m = 0; m < 4; ++m) a[m] = *(const i32x4*)&Ab[arow + m * 1024 + sl];
        #pragma unroll
        for (int n = 0; n < 4; ++n) b[n] = *(const i32x4*)&Bb[brow + n * 1024 + sl];

        // ---- stage tile t+1 (other buffer; t-1 reads retired at t-1 end barrier)
        if (t < 15) STAGE(t + 1)

        // ---- H1: a x b01
        asm volatile("s_waitcnt lgkmcnt(2)" ::: "memory");
        __builtin_amdgcn_sched_barrier(0);
        __builtin_amdgcn_s_setprio(1);
        #pragma unroll
        for (int m = 0; m < 4; ++m)
            #pragma unroll
            for (int n = 0; n < 2; ++n)
                acc[m][n] = __builtin_amdgcn_mfma_i32_16x16x64_i8(a[m], b[n], acc[m][n], 0, 0, 0);
        __builtin_amdgcn_s_setprio(0);
        // ---- H2: a x b23
        asm volatile("s_waitcnt lgkmcnt(0)" ::: "memory");
        __builtin_amdgcn_sched_barrier(0);
        __builtin_amdgcn_s_setprio(1);
        #pragma unroll
        for (int m = 0; m < 4; ++m)
            #pragma unroll
            for (int n = 2; n < 4; ++n)
                acc[m][n] = __builtin_amdgcn_mfma_i32_16x16x64_i8(a[m], b[n], acc[m][n], 0, 0, 0);
        __builtin_amdgcn_s_setprio(0);

        // ---- tile end: next tile landed, publish buffers
        if (t < 15) { asm volatile("s_waitcnt vmcnt(0)" ::: "memory"); }
        __builtin_amdgcn_s_barrier();
        __builtin_amdgcn_sched_barrier(0);
    }

    // ---- epilogue: fused min over memory dim (d2 = qq + mb2 - 2*S*dot_i32)
    if (tid < 128) rowmin[tid] = 0xFFFFFFFFu;
    __syncthreads();

    float mb2v[4];
    #pragma unroll
    for (int n = 0; n < 4; ++n) mb2v[n] = mb2[m0 + wn * 64 + n * 16 + (lane & 15)];

    #pragma unroll
    for (int m = 0; m < 4; ++m) {
        #pragma unroll
        for (int r = 0; r < 4; ++r) {
            const int qrow = wm * 64 + m * 16 + (lane >> 4) * 4 + r;
            const float qq = qn2[q0 + qrow];
            float v = 3.4e38f;
            #pragma unroll
            for (int n = 0; n < 4; ++n) {
                float d2 = qq + mb2v[n] - TWO_S * (float)acc[m][n][r];
                v = fminf(v, d2);
            }
            #pragma unroll
            for (int s = 1; s < 16; s <<= 1) v = fminf(v, __shfl_xor(v, s));
            if ((lane & 15) == 0) atomicMin(&rowmin[qrow], flipf(v));
        }
    }
    __syncthreads();
    if (tid < 128) atomicMin(minkeys + q0 + tid, rowmin[tid]);
}

// per-image max + write patch scores
__global__ __launch_bounds__(256) void final_kernel(const u32* __restrict__ keys, float* __restrict__ out) {
    int b = blockIdx.x, tid = threadIdx.x;
    float mx = -3.4e38f;
    for (int i = tid; i < 784; i += 256) {
        float f = unflipf(keys[b * 784 + i]);
        out[8 + b * 784 + i] = f;
        mx = fmaxf(mx, f);
    }
    for (int s = 32; s; s >>= 1) mx = fmaxf(mx, __shfl_down(mx, s));
    __shared__ float sm[4];
    if ((tid & 63) == 0) sm[tid >> 6] = mx;
    __syncthreads();
    if (tid == 0) out[b] = fmaxf(fmaxf(sm[0], sm[1]), fmaxf(sm[2], sm[3]));
}

extern "C" void kernel_launch(void* const* d_in, const int* in_sizes, int n_in,
                              void* d_out, int out_size, void* d_ws, size_t ws_size,
                              hipStream_t stream) {
    const float* feat2 = (const float*)d_in[0];   // [8,512,28,28]
    const float* feat3 = (const float*)d_in[1];   // [8,1024,14,14]
    const float* mb    = (const float*)d_in[2];   // [16384,1024]
    float* out = (float*)d_out;                   // [8] image + [8,28,28] patch

    char* ws = (char*)d_ws;
    float* U      = (float*)(ws);                  // 3,211,264 B
    u8*    qb     = (u8*)   (ws + 3211264);        // 6400*1024 = 6,553,600 B (pad rows unused)
    u8*    mbb    = (u8*)   (ws + 9764864);        // 16,777,216 B
    float* qn2    = (float*)(ws + 26542080);       // 25,088 B
    float* mb2    = (float*)(ws + 26567168);       // 65,536 B
    u32*   minkey = (u32*)  (ws + 26632704);       // 25,600 B

    u_init_kernel<<<3136, 256, 0, stream>>>(feat3, U, minkey, qn2);
    mbq_kernel<<<19968, 256, 0, stream>>>(mb, mbb, mb2, feat2, U, qb, qn2);
    gemm_min_kernel<<<3200, 512, 0, stream>>>(qb, mbb, qn2, mb2, minkey);
    final_kernel<<<8, 256, 0, stream>>>(minkey, out);
}